// Round 5
// baseline (470.847 us; speedup 1.0000x reference)
//
#include <hip/hip_runtime.h>

// Problem constants: B=8, S=2048, N=4, D=1024.
// out[b,s,i,d] = (sum_j h_res[b,s,i,j] * x[b,s,j,d]) * h_out[b,s,d]
//             + h_post[b,s,i] * x[b,s,i,d]
//
// ~605 MB total traffic -> ~96 us floor at the 6.29 TB/s measured copy ceiling.
//
// v4: A/B test — v2b structure WITHOUT nontemporal hints.
// Evidence so far: v2b (one-shot, nt) and v3 (persistent, pipelined, nt)
// both run the kernel at ~127 us / 4.75 TB/s -> scheduling is not the
// limiter; the shared suspect is the nt store path (bypasses L2 write-back
// buffering; the L2 normally reorders write-backs for HBM row locality —
// the harness's plain fills hit 6.5 TB/s through that path).
// This version: plain loads/stores through L2, one-shot blocks, no LDS,
// no barrier, block-uniform coefficient loads vectorized as v4f.

#define NB 8
#define NS 2048
#define NN 4
#define ND 1024

typedef float v4f __attribute__((ext_vector_type(4)));

__global__ __launch_bounds__(256) void fused_stream_mix(
    const float* __restrict__ x,      // [B*S, N, D]
    const float* __restrict__ h_res,  // [B*S, N, N]
    const float* __restrict__ h_out,  // [B*S, D]
    const float* __restrict__ h_post, // [B*S, N]
    float* __restrict__ out)          // [B*S, N, D]
{
    const int bs = blockIdx.x;        // 0 .. B*S-1
    const int t  = threadIdx.x;       // 0 .. 255 ; owns d = 4t .. 4t+3

    // Big streaming loads first: 4 x-rows + h_out, 80 B/lane in flight.
    const v4f* __restrict__ xp = (const v4f*)(x + (size_t)bs * NN * ND);
    const v4f x0 = xp[0 * (ND / 4) + t];
    const v4f x1 = xp[1 * (ND / 4) + t];
    const v4f x2 = xp[2 * (ND / 4) + t];
    const v4f x3 = xp[3 * (ND / 4) + t];
    const v4f ho = ((const v4f*)(h_out + (size_t)bs * ND))[t];

    // Block-uniform coefficients: direct loads (wave-broadcast), vectorized.
    const v4f* __restrict__ hr = (const v4f*)(h_res + (size_t)bs * (NN * NN));
    const v4f r0 = hr[0];
    const v4f r1 = hr[1];
    const v4f r2 = hr[2];
    const v4f r3 = hr[3];
    const v4f p  = *(const v4f*)(h_post + (size_t)bs * NN);

    v4f* __restrict__ op = (v4f*)(out + (size_t)bs * NN * ND);

    #pragma unroll
    for (int i = 0; i < NN; ++i) {
        const v4f rr = (i == 0) ? r0 : (i == 1) ? r1 : (i == 2) ? r2 : r3;
        const v4f xi = (i == 0) ? x0 : (i == 1) ? x1 : (i == 2) ? x2 : x3;
        const float hp = p[i];

        v4f m;
        m.x = (rr.x * x0.x + rr.y * x1.x + rr.z * x2.x + rr.w * x3.x) * ho.x + hp * xi.x;
        m.y = (rr.x * x0.y + rr.y * x1.y + rr.z * x2.y + rr.w * x3.y) * ho.y + hp * xi.y;
        m.z = (rr.x * x0.z + rr.y * x1.z + rr.z * x2.z + rr.w * x3.z) * ho.z + hp * xi.z;
        m.w = (rr.x * x0.w + rr.y * x1.w + rr.z * x2.w + rr.w * x3.w) * ho.w + hp * xi.w;

        op[i * (ND / 4) + t] = m;
    }
}

extern "C" void kernel_launch(void* const* d_in, const int* in_sizes, int n_in,
                              void* d_out, int out_size, void* d_ws, size_t ws_size,
                              hipStream_t stream) {
    const float* x      = (const float*)d_in[0];
    const float* h_res  = (const float*)d_in[1];
    const float* h_out  = (const float*)d_in[2];
    const float* h_post = (const float*)d_in[3];
    float* out = (float*)d_out;

    // One block per (b,s) position; 256 threads cover D=1024 as float4.
    fused_stream_mix<<<NB * NS, 256, 0, stream>>>(x, h_res, h_out, h_post, out);
}

// Round 6
// 461.254 us; speedup vs baseline: 1.0208x; 1.0208x over previous
//
#include <hip/hip_runtime.h>

// Problem constants: B=8, S=2048, N=4, D=1024.
// out[b,s,i,d] = (sum_j h_res[b,s,i,j] * x[b,s,j,d]) * h_out[b,s,d]
//             + h_post[b,s,i] * x[b,s,i,d]
//
// ~605 MB total traffic. Floor from measured ceilings (reads 6.1, writes
// 6.5 TB/s): ~96 us. v2b/v3 sit at ~127 us (4.77 TB/s).
//
// v5: mega-block, stream-major load ordering. A/B history: nt hints = -16us
// (v4 regression proved it), barrier removal = -3us, pipelining/persistent
// blocks = null (v3). Remaining theory: DRAM row-buffer locality — each v2b
// block offers the memory controller only small scattered windows (16KB x in
// 4KB-strided chunks, 4KB h_out). Now each block owns 4 CONSECUTIVE bs
// positions and issues all 16 x-loads in ascending address order (64KB
// contiguous), then 4 h_out loads (16KB), then computes/stores q-by-q
// (64KB ascending writes). Coefficients loaded per-q to cap VGPR.

#define NB 8
#define NS 2048
#define NN 4
#define ND 1024
#define BSPB 4                       // consecutive bs positions per block
#define GRID ((NB * NS) / BSPB)      // 4096

typedef float v4f __attribute__((ext_vector_type(4)));

__global__ __launch_bounds__(256) void fused_stream_mix(
    const float* __restrict__ x,      // [B*S, N, D]
    const float* __restrict__ h_res,  // [B*S, N, N]
    const float* __restrict__ h_out,  // [B*S, D]
    const float* __restrict__ h_post, // [B*S, N]
    float* __restrict__ out)          // [B*S, N, D]
{
    const int bs0 = blockIdx.x * BSPB;  // first of 4 consecutive bs
    const int t   = threadIdx.x;        // 0 .. 255 ; owns d = 4t .. 4t+3

    // ---- Phase 1: all x loads, ascending addresses (64KB contiguous/block)
    const v4f* __restrict__ xp = (const v4f*)(x + (size_t)bs0 * NN * ND);
    v4f xa[BSPB][NN];
    #pragma unroll
    for (int q = 0; q < BSPB; ++q)
        #pragma unroll
        for (int j = 0; j < NN; ++j)
            xa[q][j] = __builtin_nontemporal_load(
                xp + (q * NN + j) * (ND / 4) + t);

    // ---- Phase 2: h_out loads, ascending (16KB contiguous/block)
    const v4f* __restrict__ hop = (const v4f*)(h_out + (size_t)bs0 * ND);
    v4f hov[BSPB];
    #pragma unroll
    for (int q = 0; q < BSPB; ++q)
        hov[q] = __builtin_nontemporal_load(hop + q * (ND / 4) + t);

    // ---- Phase 3: per-bs compute + store (64KB ascending writes)
    v4f* __restrict__ op = (v4f*)(out + (size_t)bs0 * NN * ND);

    #pragma unroll
    for (int q = 0; q < BSPB; ++q) {
        // Block-uniform coefficients (short live range, caps VGPR use).
        const v4f* __restrict__ hr =
            (const v4f*)(h_res + (size_t)(bs0 + q) * (NN * NN));
        const v4f r0 = hr[0];
        const v4f r1 = hr[1];
        const v4f r2 = hr[2];
        const v4f r3 = hr[3];
        const v4f p  = *(const v4f*)(h_post + (size_t)(bs0 + q) * NN);
        const v4f ho = hov[q];

        #pragma unroll
        for (int i = 0; i < NN; ++i) {
            const v4f rr = (i == 0) ? r0 : (i == 1) ? r1 : (i == 2) ? r2 : r3;
            const v4f xi = xa[q][i];

            v4f m;
            m.x = (rr.x * xa[q][0].x + rr.y * xa[q][1].x + rr.z * xa[q][2].x + rr.w * xa[q][3].x) * ho.x + p[i] * xi.x;
            m.y = (rr.x * xa[q][0].y + rr.y * xa[q][1].y + rr.z * xa[q][2].y + rr.w * xa[q][3].y) * ho.y + p[i] * xi.y;
            m.z = (rr.x * xa[q][0].z + rr.y * xa[q][1].z + rr.z * xa[q][2].z + rr.w * xa[q][3].z) * ho.z + p[i] * xi.z;
            m.w = (rr.x * xa[q][0].w + rr.y * xa[q][1].w + rr.z * xa[q][2].w + rr.w * xa[q][3].w) * ho.w + p[i] * xi.w;

            __builtin_nontemporal_store(m, op + (q * NN + i) * (ND / 4) + t);
        }
    }
}

extern "C" void kernel_launch(void* const* d_in, const int* in_sizes, int n_in,
                              void* d_out, int out_size, void* d_ws, size_t ws_size,
                              hipStream_t stream) {
    const float* x      = (const float*)d_in[0];
    const float* h_res  = (const float*)d_in[1];
    const float* h_out  = (const float*)d_in[2];
    const float* h_post = (const float*)d_in[3];
    float* out = (float*)d_out;

    // 4096 blocks x 256 threads; each block owns 4 consecutive bs positions.
    fused_stream_mix<<<GRID, 256, 0, stream>>>(x, h_res, h_out, h_post, out);
}